// Round 18
// baseline (312.548 us; speedup 1.0000x reference)
//
#include <hip/hip_runtime.h>
#include <cstdint>

typedef short bf16x8 __attribute__((ext_vector_type(8)));
typedef short bf16x4 __attribute__((ext_vector_type(4)));
typedef float f32x4 __attribute__((ext_vector_type(4)));

#define NEG_MAX 3.402823466e38f
#define C_EXP2 0.1803368801111244f  // 0.125 * log2(e)

__device__ __forceinline__ unsigned short f2bf(float f) {
  uint32_t u = __builtin_bit_cast(uint32_t, f);
  u += 0x7FFFu + ((u >> 16) & 1u);
  return (unsigned short)(u >> 16);
}

__device__ __forceinline__ float bf2f(unsigned short s) {
  return __builtin_bit_cast(float, (uint32_t)s << 16);
}

__device__ __forceinline__ bf16x8 pack8(float4 x, float4 y) {
  bf16x8 r;
  r[0] = (short)f2bf(x.x); r[1] = (short)f2bf(x.y); r[2] = (short)f2bf(x.z); r[3] = (short)f2bf(x.w);
  r[4] = (short)f2bf(y.x); r[5] = (short)f2bf(y.y); r[6] = (short)f2bf(y.z); r[7] = (short)f2bf(y.w);
  return r;
}

__global__ __launch_bounds__(256) void cvt_w(const float* __restrict__ wq, const float* __restrict__ wk,
                                             const float* __restrict__ wv, const float* __restrict__ wo,
                                             unsigned short* __restrict__ out) {
  int i = blockIdx.x * 256 + threadIdx.x;
  const int sel = i >> 18;
  const int idx = i & 0x3FFFF;
  const float* src = (sel == 0) ? wq : (sel == 1) ? wk : (sel == 2) ? wv : wo;
  float4 v = reinterpret_cast<const float4*>(src)[idx];
  ushort4 o;
  o.x = f2bf(v.x); o.y = f2bf(v.y); o.z = f2bf(v.z); o.w = f2bf(v.w);
  reinterpret_cast<ushort4*>(out)[i] = o;
}

__global__ __launch_bounds__(256) void mask_scan(const float* __restrict__ mask,
                                                 int* __restrict__ flags) {
  const int blk = blockIdx.x;
  const int kt = blk & 31, qt = (blk >> 5) & 31, b = blk >> 10;
  const float* base = mask + ((size_t)b * 2048 + qt * 64) * 2048 + kt * 64;
  const int t = threadIdx.x;
  const int row = t >> 2, c0 = (t & 3) * 16;
  const float4* p = reinterpret_cast<const float4*>(base + (size_t)row * 2048 + c0);
  bool ones = true;
#pragma unroll
  for (int i = 0; i < 4; ++i) {
    float4 v = p[i];
    ones = ones && (v.x == 1.f) && (v.y == 1.f) && (v.z == 1.f) && (v.w == 1.f);
  }
  unsigned long long ball = __ballot(ones);
  __shared__ int sf[4];
  if ((t & 63) == 0) sf[t >> 6] = (ball == ~0ull) ? 1 : 0;
  __syncthreads();
  if (t == 0) flags[blk] = sf[0] & sf[1] & sf[2] & sf[3];
}

// Fused Q/K/V projection. z<2: head-split [B,H,S,64]; z==2: TILED V^T [B,H,32kt,64dk,64s].
__global__ __launch_bounds__(256) void gemm_qkv(const float* __restrict__ Aq,
                                                const float* __restrict__ Ak,
                                                const float* __restrict__ Av,
                                                const unsigned short* __restrict__ W3,
                                                const float* __restrict__ bq,
                                                const float* __restrict__ bk,
                                                const float* __restrict__ bv,
                                                unsigned short* __restrict__ Qbf,
                                                unsigned short* __restrict__ Kbf,
                                                unsigned short* __restrict__ Vtb) {
  constexpr int KD = 1024;
  __shared__ __align__(16) unsigned short Al[128 * 32];
  __shared__ __align__(16) unsigned short Bl[128 * 32];
  const int tid = threadIdx.x;
  const int l = tid & 63;
  const int w = tid >> 6;
  const int lr = l & 15;
  const int lg = l >> 4;
  const int gm = blockIdx.y;
  const int gn = blockIdx.x;
  const int z = blockIdx.z;
  const int wr = w >> 1;
  const int wc = w & 1;

  const float* Af = (z == 0) ? Aq : (z == 1) ? Ak : Av;
  const float* bias = (z == 0) ? bq : (z == 1) ? bk : bv;
  const unsigned short* Bw = W3 + (size_t)z * 1048576;
  unsigned short* Cb = (z == 0) ? Qbf : (z == 1) ? Kbf : Vtb;

  f32x4 acc[4][4];
#pragma unroll
  for (int m = 0; m < 4; ++m)
#pragma unroll
    for (int n = 0; n < 4; ++n) acc[m][n] = (f32x4){0.f, 0.f, 0.f, 0.f};

  const int c0 = w * 2;
  const int srow = (l >> 2);
  const int scol = (l & 3) * 8;
  const unsigned short* gB = Bw + (size_t)(gn * 128) * KD;

  const int arow = tid >> 1;
  const int ahalf = tid & 1;
  const float* gA = Af + (size_t)(gm * 128 + arow) * KD + ahalf * 16;

  float4 ap[4];
  {
    const float4* p = reinterpret_cast<const float4*>(gA);
#pragma unroll
    for (int i = 0; i < 4; ++i) ap[i] = p[i];
  }

  for (int kt = 0; kt < 32; ++kt) {
    const int k0 = kt * 32;
    const unsigned short* b0 = gB + (size_t)(c0 * 16 + srow) * KD + k0 + scol;
    const unsigned short* b1 = b0 + (size_t)16 * KD;
    __builtin_amdgcn_global_load_lds((const __attribute__((address_space(1))) void*)b0,
                                     (__attribute__((address_space(3))) void*)&Bl[c0 * 512], 16, 0, 0);
    __builtin_amdgcn_global_load_lds((const __attribute__((address_space(1))) void*)b1,
                                     (__attribute__((address_space(3))) void*)&Bl[c0 * 512 + 512], 16, 0, 0);
    {
      bf16x8* dst = reinterpret_cast<bf16x8*>(&Al[arow * 32 + ahalf * 16]);
      dst[0] = pack8(ap[0], ap[1]);
      dst[1] = pack8(ap[2], ap[3]);
    }
    __syncthreads();
    if (kt + 1 < 32) {
      const float4* p = reinterpret_cast<const float4*>(gA + (kt + 1) * 32);
#pragma unroll
      for (int i = 0; i < 4; ++i) ap[i] = p[i];
    }
    bf16x8 af[4], bfr[4];
#pragma unroll
    for (int m = 0; m < 4; ++m)
      af[m] = *reinterpret_cast<const bf16x8*>(&Al[(wr * 64 + m * 16 + lr) * 32 + lg * 8]);
#pragma unroll
    for (int n = 0; n < 4; ++n)
      bfr[n] = *reinterpret_cast<const bf16x8*>(&Bl[(wc * 64 + n * 16 + lr) * 32 + lg * 8]);
#pragma unroll
    for (int m = 0; m < 4; ++m)
#pragma unroll
      for (int n = 0; n < 4; ++n)
        acc[m][n] = __builtin_amdgcn_mfma_f32_16x16x32_bf16(af[m], bfr[n], acc[m][n], 0, 0, 0);
    __syncthreads();
  }

#pragma unroll
  for (int m = 0; m < 4; ++m) {
#pragma unroll
    for (int n = 0; n < 4; ++n) {
      const int colg = gn * 128 + wc * 64 + n * 16 + lr;
      const float bv2 = bias[colg];
#pragma unroll
      for (int r = 0; r < 4; ++r) {
        const int rowg = gm * 128 + wr * 64 + m * 16 + lg * 4 + r;
        const float v = acc[m][n][r] + bv2;
        const int bb = rowg >> 11, ss = rowg & 2047;
        const int hh = colg >> 6, dk = colg & 63;
        if (z < 2)
          Cb[(((size_t)bb * 16 + hh) * 2048 + ss) * 64 + dk] = f2bf(v);
        else
          Cb[(((size_t)bb * 16 + hh) * 32 + (ss >> 6)) * 4096 + (size_t)dk * 64 + (ss & 63)] = f2bf(v);
      }
    }
  }
}

// Output projection, 128x64 tiles, grid (16,32) = 512 blocks (2/CU), 4 waves (2x2),
// wave tile 64x32. LDS: A 8KB + B 4KB.
__global__ __launch_bounds__(256) void gemm_out(const unsigned short* __restrict__ A,
                                                const unsigned short* __restrict__ Bw,
                                                const float* __restrict__ bias,
                                                float* __restrict__ Cf) {
  constexpr int KD = 1024;
  __shared__ __align__(16) unsigned short Al[128 * 32];
  __shared__ __align__(16) unsigned short Bl[64 * 32];
  const int tid = threadIdx.x;
  const int l = tid & 63;
  const int w = tid >> 6;          // 0..3
  const int lr = l & 15;
  const int lg = l >> 4;
  const int gm = blockIdx.y;       // 0..31 (M tiles of 128)
  const int gn = blockIdx.x;       // 0..15 (N tiles of 64)
  const int wr = w >> 1;           // 0..1
  const int wc = w & 1;            // 0..1

  f32x4 acc[4][2];
#pragma unroll
  for (int m = 0; m < 4; ++m)
#pragma unroll
    for (int n = 0; n < 2; ++n) acc[m][n] = (f32x4){0.f, 0.f, 0.f, 0.f};

  const int srow = (l >> 2);
  const int scol = (l & 3) * 8;
  const unsigned short* gA = A + (size_t)(gm * 128) * KD;
  const unsigned short* gB = Bw + (size_t)(gn * 64) * KD;

  for (int kt = 0; kt < 32; ++kt) {
    const int k0 = kt * 32;
    const unsigned short* a0 = gA + (size_t)(w * 32 + srow) * KD + k0 + scol;
    const unsigned short* a1 = a0 + (size_t)16 * KD;
    const unsigned short* b0 = gB + (size_t)(w * 16 + srow) * KD + k0 + scol;
    __builtin_amdgcn_global_load_lds((const __attribute__((address_space(1))) void*)a0,
                                     (__attribute__((address_space(3))) void*)&Al[w * 1024], 16, 0, 0);
    __builtin_amdgcn_global_load_lds((const __attribute__((address_space(1))) void*)a1,
                                     (__attribute__((address_space(3))) void*)&Al[w * 1024 + 512], 16, 0, 0);
    __builtin_amdgcn_global_load_lds((const __attribute__((address_space(1))) void*)b0,
                                     (__attribute__((address_space(3))) void*)&Bl[w * 512], 16, 0, 0);
    __syncthreads();
    bf16x8 af[4], bfr[2];
#pragma unroll
    for (int m = 0; m < 4; ++m)
      af[m] = *reinterpret_cast<const bf16x8*>(&Al[(wr * 64 + m * 16 + lr) * 32 + lg * 8]);
#pragma unroll
    for (int n = 0; n < 2; ++n)
      bfr[n] = *reinterpret_cast<const bf16x8*>(&Bl[(wc * 32 + n * 16 + lr) * 32 + lg * 8]);
#pragma unroll
    for (int m = 0; m < 4; ++m)
#pragma unroll
      for (int n = 0; n < 2; ++n)
        acc[m][n] = __builtin_amdgcn_mfma_f32_16x16x32_bf16(af[m], bfr[n], acc[m][n], 0, 0, 0);
    __syncthreads();
  }

#pragma unroll
  for (int m = 0; m < 4; ++m) {
#pragma unroll
    for (int n = 0; n < 2; ++n) {
      const int colg = gn * 64 + wc * 32 + n * 16 + lr;
      const float bv = bias[colg];
#pragma unroll
      for (int r = 0; r < 4; ++r) {
        const int rowg = gm * 128 + wr * 64 + m * 16 + lg * 4 + r;
        Cf[(size_t)rowg * 1024 + colg] = acc[m][n][r] + bv;
      }
    }
  }
}

// Attention: one block = (b,h,128 q-rows), 8 waves x 16 rows, 512 blocks.
// Phase 1: ring-6 K, TWO tiles per barrier, counted vmcnt(2) (16 barrier-steps).
// Phase 2: K/V dbuf (slots 0-3), counted vmcnt(4); coalesced f32x4 weight stores
// (PLAIN stores this round: L2-acked, A/B vs NT).
__global__ __launch_bounds__(512, 4) void attn_fused(const unsigned short* __restrict__ Q,
                                                     const unsigned short* __restrict__ Kb,
                                                     const unsigned short* __restrict__ Vt,
                                                     const float* __restrict__ mask,
                                                     const int* __restrict__ flags,
                                                     float* __restrict__ wout,
                                                     unsigned short* __restrict__ ctx) {
  const int tid = threadIdx.x;
  const int l = tid & 63;
  const int w = tid >> 6;          // 0..7
  const int lr = l & 15;
  const int lg = l >> 4;

  const int d = blockIdx.x;
  const int bh = (d >> 7) * 8 + (d & 7);
  const int qp = (d >> 3) & 15;
  const int b = bh >> 4, h = bh & 15;
  const int q0 = qp * 128;

  __shared__ __align__(16) unsigned short KV[6][4096];   // 48 KB (ph1 ring-6; ph2 uses 0-3)
  __shared__ __align__(16) unsigned short Wl[8][16][64]; // 16 KB, per-wave-private

  const size_t qoff = ((size_t)bh * 2048 + (q0 + w * 16 + lr)) * 64 + lg * 8;
  const bf16x8 qf0 = *reinterpret_cast<const bf16x8*>(Q + qoff);
  const bf16x8 qf1 = *reinterpret_cast<const bf16x8*>(Q + qoff + 32);

  const int seg = tid;
  const int rs = seg >> 3, cx = (seg & 7) ^ (rs & 7);
  const unsigned short* kB = Kb + (size_t)bh * 131072;
  const unsigned short* vB = Vt + (size_t)bh * 131072;   // tiled: tile kt at kt*4096
  const size_t tS = (size_t)rs * 64 + cx * 8;
  const int ldsOff = w * 512;                            // shorts

  const int sA = (lg ^ (lr & 7)) << 3;
  const int sBo = ((4 + lg) ^ (lr & 7)) << 3;

  const int fbase = (b * 32 + qp * 2 + (w >> 2)) * 32;
  const uint32_t fmask = (uint32_t)__ballot(flags[fbase + (l & 31)] != 0);

  const float* mbase = mask + (size_t)b * 2048 * 2048;

  // W readback geometry (coalesced): store i -> row 4i+(l>>4), cols (l&15)*4..+3
  const int lc = l & 15;
  const int wsub = (lc & 1) * 4;
  const int wcch = lc >> 1;

#define STAGE(base_, kt_, slot_)                                                                       \
  do {                                                                                                 \
    __builtin_amdgcn_global_load_lds(                                                                  \
        (const __attribute__((address_space(1))) void*)((base_) + (size_t)(kt_) * 4096 + tS),          \
        (__attribute__((address_space(3))) void*)(&KV[slot_][0] + ldsOff), 16, 0, 0);                  \
  } while (0)

  float s0[4] = {0.f, 0.f, 0.f, 0.f};

  // ---------------- Phase 1: denominators (ring-6, 2 tiles/barrier) ----------------
  STAGE(kB, 0, 0);
  STAGE(kB, 1, 1);
  STAGE(kB, 2, 2);
  STAGE(kB, 3, 3);
  for (int it = 0; it < 16; ++it) {
    if (it < 15) {
      asm volatile("s_waitcnt vmcnt(2)" ::: "memory");
    } else {
      asm volatile("s_waitcnt vmcnt(0)" ::: "memory");
    }
    __builtin_amdgcn_s_barrier();
    __builtin_amdgcn_sched_barrier(0);
    const int kt0 = it * 2;
#pragma unroll
    for (int half = 0; half < 2; ++half) {
      const int kt = kt0 + half;
      const unsigned short* Ks = &KV[kt % 6][0];
      bf16x8 kf0[4], kf1[4];
#pragma unroll
      for (int n = 0; n < 4; ++n) {
        const int rb = (n * 16 + lr) * 64;
        kf0[n] = *reinterpret_cast<const bf16x8*>(&Ks[rb + sA]);
        kf1[n] = *reinterpret_cast<const bf16x8*>(&Ks[rb + sBo]);
      }
      if (kt + 4 < 32) STAGE(kB, kt + 4, (kt + 4) % 6);
      f32x4 acc[4];
#pragma unroll
      for (int n = 0; n < 4; ++n) {
        acc[n] = (f32x4){0.f, 0.f, 0.f, 0.f};
        acc[n] = __builtin_amdgcn_mfma_f32_16x16x32_bf16(qf0, kf0[n], acc[n], 0, 0, 0);
        acc[n] = __builtin_amdgcn_mfma_f32_16x16x32_bf16(qf1, kf1[n], acc[n], 0, 0, 0);
      }
      if ((fmask >> kt) & 1) {
#pragma unroll
        for (int r = 0; r < 4; ++r)
          s0[r] += exp2f(acc[0][r] * C_EXP2) + exp2f(acc[1][r] * C_EXP2) +
                   exp2f(acc[2][r] * C_EXP2) + exp2f(acc[3][r] * C_EXP2);
      } else {
#pragma unroll
        for (int r = 0; r < 4; ++r) {
          const int qrow = q0 + w * 16 + lg * 4 + r;
          const float* mp = mbase + (size_t)qrow * 2048 + kt * 64;
          float ps = 0.f;
#pragma unroll
          for (int n = 0; n < 4; ++n) {
            const float mv = mp[n * 16 + lr];
            ps += __expf(acc[n][r] * 0.125f + (1.0f - mv) * (-NEG_MAX));
          }
          s0[r] += ps;
        }
      }
    }
  }

  float inv_s[4];
#pragma unroll
  for (int r = 0; r < 4; ++r) {
#pragma unroll
    for (int dd = 1; dd < 16; dd <<= 1) s0[r] += __shfl_xor(s0[r], dd);
    inv_s[r] = 1.0f / s0[r];
  }

  f32x4 cacc[4];
#pragma unroll
  for (int n = 0; n < 4; ++n) cacc[n] = (f32x4){0.f, 0.f, 0.f, 0.f};

  // ---------------- Phase 2: weights + PV (dbuf, counted vmcnt) ----------------
  STAGE(kB, 0, 0);
  STAGE(vB, 0, 2);
  for (int kt = 0; kt < 32; ++kt) {
    const int cur = kt & 1;
    if (kt == 0) {
      asm volatile("s_waitcnt vmcnt(0)" ::: "memory");
    } else {
      asm volatile("s_waitcnt vmcnt(4)" ::: "memory");  // drains 2 stage loads (older); 4 stores stay in flight
    }
    __builtin_amdgcn_s_barrier();
    __builtin_amdgcn_sched_barrier(0);
    const unsigned short* Ks = &KV[cur][0];
    const unsigned short* Vs = &KV[2 + cur][0];
    bf16x8 kf0[4], kf1[4];
#pragma unroll
    for (int n = 0; n < 4; ++n) {
      const int rb = (n * 16 + lr) * 64;
      kf0[n] = *reinterpret_cast<const bf16x8*>(&Ks[rb + sA]);
      kf1[n] = *reinterpret_cast<const bf16x8*>(&Ks[rb + sBo]);
    }
    if (kt + 1 < 32) {
      STAGE(kB, kt + 1, cur ^ 1);
      STAGE(vB, kt + 1, 2 + (cur ^ 1));
    }
    f32x4 acc[4];
#pragma unroll
    for (int n = 0; n < 4; ++n) {
      acc[n] = (f32x4){0.f, 0.f, 0.f, 0.f};
      acc[n] = __builtin_amdgcn_mfma_f32_16x16x32_bf16(qf0, kf0[n], acc[n], 0, 0, 0);
      acc[n] = __builtin_amdgcn_mfma_f32_16x16x32_bf16(qf1, kf1[n], acc[n], 0, 0, 0);
    }
    const int fl = (fmask >> kt) & 1;
#pragma unroll
    for (int r = 0; r < 4; ++r) {
      const int row2 = lg * 4 + r;
      const int rx = (row2 & 7) << 3;
      if (fl) {
#pragma unroll
        for (int n = 0; n < 4; ++n) {
          const float wgt = exp2f(acc[n][r] * C_EXP2) * inv_s[r];
          Wl[w][row2][(n * 16 + lr) ^ rx] = f2bf(wgt);
        }
      } else {
        const int qrow = q0 + w * 16 + row2;
        const float* mp = mbase + (size_t)qrow * 2048 + kt * 64;
#pragma unroll
        for (int n = 0; n < 4; ++n) {
          const float mv = mp[n * 16 + lr];
          const float wgt = __expf(acc[n][r] * 0.125f + (1.0f - mv) * (-NEG_MAX)) * inv_s[r];
          Wl[w][row2][(n * 16 + lr) ^ rx] = f2bf(wgt);
        }
      }
    }
    bf16x8 vf0[4], vf1[4];
#pragma unroll
    for (int n = 0; n < 4; ++n) {
      const int rb = (n * 16 + lr) * 64;
      vf0[n] = *reinterpret_cast<const bf16x8*>(&Vs[rb + sA]);
      vf1[n] = *reinterpret_cast<const bf16x8*>(&Vs[rb + sBo]);
    }
    asm volatile("s_waitcnt lgkmcnt(0)" ::: "memory");
    __builtin_amdgcn_sched_barrier(0);
    // W readback -> coalesced f32x4 PLAIN stores (L2-acked; A/B vs NT)
    {
#pragma unroll
      for (int i = 0; i < 4; ++i) {
        const int row = i * 4 + (l >> 4);
        const int addr = ((wcch ^ (row & 7)) << 3) + wsub;
        const bf16x4 wb = *reinterpret_cast<const bf16x4*>(&Wl[w][row][addr]);
        f32x4 fo;
        fo[0] = bf2f((unsigned short)wb[0]);
        fo[1] = bf2f((unsigned short)wb[1]);
        fo[2] = bf2f((unsigned short)wb[2]);
        fo[3] = bf2f((unsigned short)wb[3]);
        f32x4* wpv = reinterpret_cast<f32x4*>(
            wout + ((size_t)bh * 2048 + q0 + w * 16 + row) * 2048 + kt * 64 + lc * 4);
        *wpv = fo;
      }
    }
    const bf16x8 a0 = *reinterpret_cast<const bf16x8*>(&Wl[w][lr][(lg ^ (lr & 7)) * 8]);
    const bf16x8 a1 = *reinterpret_cast<const bf16x8*>(&Wl[w][lr][((4 | lg) ^ (lr & 7)) * 8]);
#pragma unroll
    for (int n = 0; n < 4; ++n) {
      cacc[n] = __builtin_amdgcn_mfma_f32_16x16x32_bf16(a0, vf0[n], cacc[n], 0, 0, 0);
      cacc[n] = __builtin_amdgcn_mfma_f32_16x16x32_bf16(a1, vf1[n], cacc[n], 0, 0, 0);
    }
  }

#pragma unroll
  for (int n = 0; n < 4; ++n) {
#pragma unroll
    for (int r = 0; r < 4; ++r) {
      const int ss = q0 + w * 16 + lg * 4 + r;
      const int col = h * 64 + n * 16 + lr;
      ctx[((size_t)b * 2048 + ss) * 1024 + col] = f2bf(cacc[n][r]);
    }
  }
#undef STAGE
}

extern "C" void kernel_launch(void* const* d_in, const int* in_sizes, int n_in,
                              void* d_out, int out_size, void* d_ws, size_t ws_size,
                              hipStream_t stream) {
  const float* query = (const float*)d_in[0];
  const float* key   = (const float*)d_in[1];
  const float* value = (const float*)d_in[2];
  const float* mask  = (const float*)d_in[3];
  const float* wq = (const float*)d_in[4];
  const float* bq = (const float*)d_in[5];
  const float* wk = (const float*)d_in[6];
  const float* bk = (const float*)d_in[7];
  const float* wv = (const float*)d_in[8];
  const float* bv = (const float*)d_in[9];
  const float* wo = (const float*)d_in[10];
  const float* bo = (const float*)d_in[11];

  unsigned short* Qbf = (unsigned short*)d_ws;      // [B,H,S,64] bf16   8 MB
  unsigned short* Kbf = Qbf + 4194304;              // [B,H,S,64] bf16   8 MB
  unsigned short* Vtb = Kbf + 4194304;              // tiled V^T          8 MB
  unsigned short* ctx = Vtb + 4194304;              // [B,S,1024] bf16   8 MB
  unsigned short* wbf4 = ctx + 4194304;             // wq|wk|wv|wo bf16  8 MB
  int* flags = (int*)(wbf4 + 4194304);              // [B,32,32] flags   8 KB

  float* outp = (float*)d_out;            // [B,S,1024] fp32
  float* wout = outp + 4194304;           // [B,H,S,S] fp32

  mask_scan<<<2048, 256, 0, stream>>>(mask, flags);
  cvt_w<<<4096, 256, 0, stream>>>(wq, wk, wv, wo, wbf4);

  dim3 gq(8, 32, 3);
  gemm_qkv<<<gq, 256, 0, stream>>>(query, key, value, wbf4, bq, bk, bv, Qbf, Kbf, Vtb);

  attn_fused<<<512, 512, 0, stream>>>(Qbf, Kbf, Vtb, mask, flags, wout, ctx);

  dim3 gg(16, 32);
  gemm_out<<<gg, 256, 0, stream>>>(ctx, wbf4 + 3145728, bo, outp);
}

// Round 19
// 256.609 us; speedup vs baseline: 1.2180x; 1.2180x over previous
//
#include <hip/hip_runtime.h>
#include <cstdint>

typedef short bf16x8 __attribute__((ext_vector_type(8)));
typedef short bf16x4 __attribute__((ext_vector_type(4)));
typedef float f32x4 __attribute__((ext_vector_type(4)));

#define NEG_MAX 3.402823466e38f
#define C_EXP2 0.1803368801111244f  // 0.125 * log2(e)

__device__ __forceinline__ unsigned short f2bf(float f) {
  uint32_t u = __builtin_bit_cast(uint32_t, f);
  u += 0x7FFFu + ((u >> 16) & 1u);
  return (unsigned short)(u >> 16);
}

__device__ __forceinline__ float bf2f(unsigned short s) {
  return __builtin_bit_cast(float, (uint32_t)s << 16);
}

__device__ __forceinline__ bf16x8 pack8(float4 x, float4 y) {
  bf16x8 r;
  r[0] = (short)f2bf(x.x); r[1] = (short)f2bf(x.y); r[2] = (short)f2bf(x.z); r[3] = (short)f2bf(x.w);
  r[4] = (short)f2bf(y.x); r[5] = (short)f2bf(y.y); r[6] = (short)f2bf(y.z); r[7] = (short)f2bf(y.w);
  return r;
}

// Merged prep: blocks 0..2047 = mask_scan tiles; blocks 2048..6143 = weight cvt.
__global__ __launch_bounds__(256) void prep(const float* __restrict__ mask,
                                            int* __restrict__ flags,
                                            const float* __restrict__ wq, const float* __restrict__ wk,
                                            const float* __restrict__ wv, const float* __restrict__ wo,
                                            unsigned short* __restrict__ out) {
  const int blk = blockIdx.x;
  const int t = threadIdx.x;
  if (blk < 2048) {
    const int kt = blk & 31, qt = (blk >> 5) & 31, b = blk >> 10;
    const float* base = mask + ((size_t)b * 2048 + qt * 64) * 2048 + kt * 64;
    const int row = t >> 2, c0 = (t & 3) * 16;
    const float4* p = reinterpret_cast<const float4*>(base + (size_t)row * 2048 + c0);
    bool ones = true;
#pragma unroll
    for (int i = 0; i < 4; ++i) {
      float4 v = p[i];
      ones = ones && (v.x == 1.f) && (v.y == 1.f) && (v.z == 1.f) && (v.w == 1.f);
    }
    unsigned long long ball = __ballot(ones);
    __shared__ int sf[4];
    if ((t & 63) == 0) sf[t >> 6] = (ball == ~0ull) ? 1 : 0;
    __syncthreads();
    if (t == 0) flags[blk] = sf[0] & sf[1] & sf[2] & sf[3];
  } else {
    int i = (blk - 2048) * 256 + t;
    const int sel = i >> 18;
    const int idx = i & 0x3FFFF;
    const float* src = (sel == 0) ? wq : (sel == 1) ? wk : (sel == 2) ? wv : wo;
    float4 v = reinterpret_cast<const float4*>(src)[idx];
    ushort4 o;
    o.x = f2bf(v.x); o.y = f2bf(v.y); o.z = f2bf(v.z); o.w = f2bf(v.w);
    reinterpret_cast<ushort4*>(out)[i] = o;
  }
}

// Fused Q/K/V projection. z<2: head-split [B,H,S,64]; z==2: TILED V^T [B,H,32kt,64dk,64s].
__global__ __launch_bounds__(256) void gemm_qkv(const float* __restrict__ Aq,
                                                const float* __restrict__ Ak,
                                                const float* __restrict__ Av,
                                                const unsigned short* __restrict__ W3,
                                                const float* __restrict__ bq,
                                                const float* __restrict__ bk,
                                                const float* __restrict__ bv,
                                                unsigned short* __restrict__ Qbf,
                                                unsigned short* __restrict__ Kbf,
                                                unsigned short* __restrict__ Vtb) {
  constexpr int KD = 1024;
  __shared__ __align__(16) unsigned short Al[128 * 32];
  __shared__ __align__(16) unsigned short Bl[128 * 32];
  const int tid = threadIdx.x;
  const int l = tid & 63;
  const int w = tid >> 6;
  const int lr = l & 15;
  const int lg = l >> 4;
  const int gm = blockIdx.y;
  const int gn = blockIdx.x;
  const int z = blockIdx.z;
  const int wr = w >> 1;
  const int wc = w & 1;

  const float* Af = (z == 0) ? Aq : (z == 1) ? Ak : Av;
  const float* bias = (z == 0) ? bq : (z == 1) ? bk : bv;
  const unsigned short* Bw = W3 + (size_t)z * 1048576;
  unsigned short* Cb = (z == 0) ? Qbf : (z == 1) ? Kbf : Vtb;

  f32x4 acc[4][4];
#pragma unroll
  for (int m = 0; m < 4; ++m)
#pragma unroll
    for (int n = 0; n < 4; ++n) acc[m][n] = (f32x4){0.f, 0.f, 0.f, 0.f};

  const int c0 = w * 2;
  const int srow = (l >> 2);
  const int scol = (l & 3) * 8;
  const unsigned short* gB = Bw + (size_t)(gn * 128) * KD;

  const int arow = tid >> 1;
  const int ahalf = tid & 1;
  const float* gA = Af + (size_t)(gm * 128 + arow) * KD + ahalf * 16;

  float4 ap[4];
  {
    const float4* p = reinterpret_cast<const float4*>(gA);
#pragma unroll
    for (int i = 0; i < 4; ++i) ap[i] = p[i];
  }

  for (int kt = 0; kt < 32; ++kt) {
    const int k0 = kt * 32;
    const unsigned short* b0 = gB + (size_t)(c0 * 16 + srow) * KD + k0 + scol;
    const unsigned short* b1 = b0 + (size_t)16 * KD;
    __builtin_amdgcn_global_load_lds((const __attribute__((address_space(1))) void*)b0,
                                     (__attribute__((address_space(3))) void*)&Bl[c0 * 512], 16, 0, 0);
    __builtin_amdgcn_global_load_lds((const __attribute__((address_space(1))) void*)b1,
                                     (__attribute__((address_space(3))) void*)&Bl[c0 * 512 + 512], 16, 0, 0);
    {
      bf16x8* dst = reinterpret_cast<bf16x8*>(&Al[arow * 32 + ahalf * 16]);
      dst[0] = pack8(ap[0], ap[1]);
      dst[1] = pack8(ap[2], ap[3]);
    }
    __syncthreads();
    if (kt + 1 < 32) {
      const float4* p = reinterpret_cast<const float4*>(gA + (kt + 1) * 32);
#pragma unroll
      for (int i = 0; i < 4; ++i) ap[i] = p[i];
    }
    bf16x8 af[4], bfr[4];
#pragma unroll
    for (int m = 0; m < 4; ++m)
      af[m] = *reinterpret_cast<const bf16x8*>(&Al[(wr * 64 + m * 16 + lr) * 32 + lg * 8]);
#pragma unroll
    for (int n = 0; n < 4; ++n)
      bfr[n] = *reinterpret_cast<const bf16x8*>(&Bl[(wc * 64 + n * 16 + lr) * 32 + lg * 8]);
#pragma unroll
    for (int m = 0; m < 4; ++m)
#pragma unroll
      for (int n = 0; n < 4; ++n)
        acc[m][n] = __builtin_amdgcn_mfma_f32_16x16x32_bf16(af[m], bfr[n], acc[m][n], 0, 0, 0);
    __syncthreads();
  }

#pragma unroll
  for (int m = 0; m < 4; ++m) {
#pragma unroll
    for (int n = 0; n < 4; ++n) {
      const int colg = gn * 128 + wc * 64 + n * 16 + lr;
      const float bv2 = bias[colg];
#pragma unroll
      for (int r = 0; r < 4; ++r) {
        const int rowg = gm * 128 + wr * 64 + m * 16 + lg * 4 + r;
        const float v = acc[m][n][r] + bv2;
        const int bb = rowg >> 11, ss = rowg & 2047;
        const int hh = colg >> 6, dk = colg & 63;
        if (z < 2)
          Cb[(((size_t)bb * 16 + hh) * 2048 + ss) * 64 + dk] = f2bf(v);
        else
          Cb[(((size_t)bb * 16 + hh) * 32 + (ss >> 6)) * 4096 + (size_t)dk * 64 + (ss & 63)] = f2bf(v);
      }
    }
  }
}

// Output projection, 128x64 tiles, grid (16,32) = 512 blocks (2/CU), 4 waves (2x2).
__global__ __launch_bounds__(256) void gemm_out(const unsigned short* __restrict__ A,
                                                const unsigned short* __restrict__ Bw,
                                                const float* __restrict__ bias,
                                                float* __restrict__ Cf) {
  constexpr int KD = 1024;
  __shared__ __align__(16) unsigned short Al[128 * 32];
  __shared__ __align__(16) unsigned short Bl[64 * 32];
  const int tid = threadIdx.x;
  const int l = tid & 63;
  const int w = tid >> 6;          // 0..3
  const int lr = l & 15;
  const int lg = l >> 4;
  const int gm = blockIdx.y;
  const int gn = blockIdx.x;
  const int wr = w >> 1;
  const int wc = w & 1;

  f32x4 acc[4][2];
#pragma unroll
  for (int m = 0; m < 4; ++m)
#pragma unroll
    for (int n = 0; n < 2; ++n) acc[m][n] = (f32x4){0.f, 0.f, 0.f, 0.f};

  const int srow = (l >> 2);
  const int scol = (l & 3) * 8;
  const unsigned short* gA = A + (size_t)(gm * 128) * KD;
  const unsigned short* gB = Bw + (size_t)(gn * 64) * KD;

  for (int kt = 0; kt < 32; ++kt) {
    const int k0 = kt * 32;
    const unsigned short* a0 = gA + (size_t)(w * 32 + srow) * KD + k0 + scol;
    const unsigned short* a1 = a0 + (size_t)16 * KD;
    const unsigned short* b0 = gB + (size_t)(w * 16 + srow) * KD + k0 + scol;
    __builtin_amdgcn_global_load_lds((const __attribute__((address_space(1))) void*)a0,
                                     (__attribute__((address_space(3))) void*)&Al[w * 1024], 16, 0, 0);
    __builtin_amdgcn_global_load_lds((const __attribute__((address_space(1))) void*)a1,
                                     (__attribute__((address_space(3))) void*)&Al[w * 1024 + 512], 16, 0, 0);
    __builtin_amdgcn_global_load_lds((const __attribute__((address_space(1))) void*)b0,
                                     (__attribute__((address_space(3))) void*)&Bl[w * 512], 16, 0, 0);
    __syncthreads();
    bf16x8 af[4], bfr[2];
#pragma unroll
    for (int m = 0; m < 4; ++m)
      af[m] = *reinterpret_cast<const bf16x8*>(&Al[(wr * 64 + m * 16 + lr) * 32 + lg * 8]);
#pragma unroll
    for (int n = 0; n < 2; ++n)
      bfr[n] = *reinterpret_cast<const bf16x8*>(&Bl[(wc * 32 + n * 16 + lr) * 32 + lg * 8]);
#pragma unroll
    for (int m = 0; m < 4; ++m)
#pragma unroll
      for (int n = 0; n < 2; ++n)
        acc[m][n] = __builtin_amdgcn_mfma_f32_16x16x32_bf16(af[m], bfr[n], acc[m][n], 0, 0, 0);
    __syncthreads();
  }

#pragma unroll
  for (int m = 0; m < 4; ++m) {
#pragma unroll
    for (int n = 0; n < 2; ++n) {
      const int colg = gn * 64 + wc * 32 + n * 16 + lr;
      const float bv = bias[colg];
#pragma unroll
      for (int r = 0; r < 4; ++r) {
        const int rowg = gm * 128 + wr * 64 + m * 16 + lg * 4 + r;
        Cf[(size_t)rowg * 1024 + colg] = acc[m][n][r] + bv;
      }
    }
  }
}

// Attention (R17-proven best): 512 blocks x 8 waves; ring-6 phase 1, dbuf phase 2,
// counted vmcnt, coalesced f32x4 NT weight stores.
__global__ __launch_bounds__(512, 4) void attn_fused(const unsigned short* __restrict__ Q,
                                                     const unsigned short* __restrict__ Kb,
                                                     const unsigned short* __restrict__ Vt,
                                                     const float* __restrict__ mask,
                                                     const int* __restrict__ flags,
                                                     float* __restrict__ wout,
                                                     unsigned short* __restrict__ ctx) {
  const int tid = threadIdx.x;
  const int l = tid & 63;
  const int w = tid >> 6;          // 0..7
  const int lr = l & 15;
  const int lg = l >> 4;

  const int d = blockIdx.x;
  const int bh = (d >> 7) * 8 + (d & 7);
  const int qp = (d >> 3) & 15;
  const int b = bh >> 4, h = bh & 15;
  const int q0 = qp * 128;

  __shared__ __align__(16) unsigned short KV[6][4096];   // 48 KB
  __shared__ __align__(16) unsigned short Wl[8][16][64]; // 16 KB, per-wave-private

  const size_t qoff = ((size_t)bh * 2048 + (q0 + w * 16 + lr)) * 64 + lg * 8;
  const bf16x8 qf0 = *reinterpret_cast<const bf16x8*>(Q + qoff);
  const bf16x8 qf1 = *reinterpret_cast<const bf16x8*>(Q + qoff + 32);

  const int seg = tid;
  const int rs = seg >> 3, cx = (seg & 7) ^ (rs & 7);
  const unsigned short* kB = Kb + (size_t)bh * 131072;
  const unsigned short* vB = Vt + (size_t)bh * 131072;
  const size_t tS = (size_t)rs * 64 + cx * 8;
  const int ldsOff = w * 512;

  const int sA = (lg ^ (lr & 7)) << 3;
  const int sBo = ((4 + lg) ^ (lr & 7)) << 3;

  const int fbase = (b * 32 + qp * 2 + (w >> 2)) * 32;
  const uint32_t fmask = (uint32_t)__ballot(flags[fbase + (l & 31)] != 0);

  const float* mbase = mask + (size_t)b * 2048 * 2048;

  const int lc = l & 15;
  const int wsub = (lc & 1) * 4;
  const int wcch = lc >> 1;

#define STAGE(base_, kt_, slot_)                                                                       \
  do {                                                                                                 \
    __builtin_amdgcn_global_load_lds(                                                                  \
        (const __attribute__((address_space(1))) void*)((base_) + (size_t)(kt_) * 4096 + tS),          \
        (__attribute__((address_space(3))) void*)(&KV[slot_][0] + ldsOff), 16, 0, 0);                  \
  } while (0)

  float s0[4] = {0.f, 0.f, 0.f, 0.f};

  // ---------------- Phase 1: denominators (ring-6, 2 tiles/barrier) ----------------
  STAGE(kB, 0, 0);
  STAGE(kB, 1, 1);
  STAGE(kB, 2, 2);
  STAGE(kB, 3, 3);
  for (int it = 0; it < 16; ++it) {
    if (it < 15) {
      asm volatile("s_waitcnt vmcnt(2)" ::: "memory");
    } else {
      asm volatile("s_waitcnt vmcnt(0)" ::: "memory");
    }
    __builtin_amdgcn_s_barrier();
    __builtin_amdgcn_sched_barrier(0);
    const int kt0 = it * 2;
#pragma unroll
    for (int half = 0; half < 2; ++half) {
      const int kt = kt0 + half;
      const unsigned short* Ks = &KV[kt % 6][0];
      bf16x8 kf0[4], kf1[4];
#pragma unroll
      for (int n = 0; n < 4; ++n) {
        const int rb = (n * 16 + lr) * 64;
        kf0[n] = *reinterpret_cast<const bf16x8*>(&Ks[rb + sA]);
        kf1[n] = *reinterpret_cast<const bf16x8*>(&Ks[rb + sBo]);
      }
      if (kt + 4 < 32) STAGE(kB, kt + 4, (kt + 4) % 6);
      f32x4 acc[4];
#pragma unroll
      for (int n = 0; n < 4; ++n) {
        acc[n] = (f32x4){0.f, 0.f, 0.f, 0.f};
        acc[n] = __builtin_amdgcn_mfma_f32_16x16x32_bf16(qf0, kf0[n], acc[n], 0, 0, 0);
        acc[n] = __builtin_amdgcn_mfma_f32_16x16x32_bf16(qf1, kf1[n], acc[n], 0, 0, 0);
      }
      if ((fmask >> kt) & 1) {
#pragma unroll
        for (int r = 0; r < 4; ++r)
          s0[r] += exp2f(acc[0][r] * C_EXP2) + exp2f(acc[1][r] * C_EXP2) +
                   exp2f(acc[2][r] * C_EXP2) + exp2f(acc[3][r] * C_EXP2);
      } else {
#pragma unroll
        for (int r = 0; r < 4; ++r) {
          const int qrow = q0 + w * 16 + lg * 4 + r;
          const float* mp = mbase + (size_t)qrow * 2048 + kt * 64;
          float ps = 0.f;
#pragma unroll
          for (int n = 0; n < 4; ++n) {
            const float mv = mp[n * 16 + lr];
            ps += __expf(acc[n][r] * 0.125f + (1.0f - mv) * (-NEG_MAX));
          }
          s0[r] += ps;
        }
      }
    }
  }

  float inv_s[4];
#pragma unroll
  for (int r = 0; r < 4; ++r) {
#pragma unroll
    for (int dd = 1; dd < 16; dd <<= 1) s0[r] += __shfl_xor(s0[r], dd);
    inv_s[r] = 1.0f / s0[r];
  }

  f32x4 cacc[4];
#pragma unroll
  for (int n = 0; n < 4; ++n) cacc[n] = (f32x4){0.f, 0.f, 0.f, 0.f};

  // ---------------- Phase 2: weights + PV (dbuf, counted vmcnt) ----------------
  STAGE(kB, 0, 0);
  STAGE(vB, 0, 2);
  for (int kt = 0; kt < 32; ++kt) {
    const int cur = kt & 1;
    if (kt == 0) {
      asm volatile("s_waitcnt vmcnt(0)" ::: "memory");
    } else {
      asm volatile("s_waitcnt vmcnt(4)" ::: "memory");
    }
    __builtin_amdgcn_s_barrier();
    __builtin_amdgcn_sched_barrier(0);
    const unsigned short* Ks = &KV[cur][0];
    const unsigned short* Vs = &KV[2 + cur][0];
    bf16x8 kf0[4], kf1[4];
#pragma unroll
    for (int n = 0; n < 4; ++n) {
      const int rb = (n * 16 + lr) * 64;
      kf0[n] = *reinterpret_cast<const bf16x8*>(&Ks[rb + sA]);
      kf1[n] = *reinterpret_cast<const bf16x8*>(&Ks[rb + sBo]);
    }
    if (kt + 1 < 32) {
      STAGE(kB, kt + 1, cur ^ 1);
      STAGE(vB, kt + 1, 2 + (cur ^ 1));
    }
    f32x4 acc[4];
#pragma unroll
    for (int n = 0; n < 4; ++n) {
      acc[n] = (f32x4){0.f, 0.f, 0.f, 0.f};
      acc[n] = __builtin_amdgcn_mfma_f32_16x16x32_bf16(qf0, kf0[n], acc[n], 0, 0, 0);
      acc[n] = __builtin_amdgcn_mfma_f32_16x16x32_bf16(qf1, kf1[n], acc[n], 0, 0, 0);
    }
    const int fl = (fmask >> kt) & 1;
#pragma unroll
    for (int r = 0; r < 4; ++r) {
      const int row2 = lg * 4 + r;
      const int rx = (row2 & 7) << 3;
      if (fl) {
#pragma unroll
        for (int n = 0; n < 4; ++n) {
          const float wgt = exp2f(acc[n][r] * C_EXP2) * inv_s[r];
          Wl[w][row2][(n * 16 + lr) ^ rx] = f2bf(wgt);
        }
      } else {
        const int qrow = q0 + w * 16 + row2;
        const float* mp = mbase + (size_t)qrow * 2048 + kt * 64;
#pragma unroll
        for (int n = 0; n < 4; ++n) {
          const float mv = mp[n * 16 + lr];
          const float wgt = __expf(acc[n][r] * 0.125f + (1.0f - mv) * (-NEG_MAX)) * inv_s[r];
          Wl[w][row2][(n * 16 + lr) ^ rx] = f2bf(wgt);
        }
      }
    }
    bf16x8 vf0[4], vf1[4];
#pragma unroll
    for (int n = 0; n < 4; ++n) {
      const int rb = (n * 16 + lr) * 64;
      vf0[n] = *reinterpret_cast<const bf16x8*>(&Vs[rb + sA]);
      vf1[n] = *reinterpret_cast<const bf16x8*>(&Vs[rb + sBo]);
    }
    asm volatile("s_waitcnt lgkmcnt(0)" ::: "memory");
    __builtin_amdgcn_sched_barrier(0);
    // W readback -> coalesced f32x4 NT stores
    {
#pragma unroll
      for (int i = 0; i < 4; ++i) {
        const int row = i * 4 + (l >> 4);
        const int addr = ((wcch ^ (row & 7)) << 3) + wsub;
        const bf16x4 wb = *reinterpret_cast<const bf16x4*>(&Wl[w][row][addr]);
        f32x4 fo;
        fo[0] = bf2f((unsigned short)wb[0]);
        fo[1] = bf2f((unsigned short)wb[1]);
        fo[2] = bf2f((unsigned short)wb[2]);
        fo[3] = bf2f((unsigned short)wb[3]);
        f32x4* wpv = reinterpret_cast<f32x4*>(
            wout + ((size_t)bh * 2048 + q0 + w * 16 + row) * 2048 + kt * 64 + lc * 4);
        __builtin_nontemporal_store(fo, wpv);
      }
    }
    const bf16x8 a0 = *reinterpret_cast<const bf16x8*>(&Wl[w][lr][(lg ^ (lr & 7)) * 8]);
    const bf16x8 a1 = *reinterpret_cast<const bf16x8*>(&Wl[w][lr][((4 | lg) ^ (lr & 7)) * 8]);
#pragma unroll
    for (int n = 0; n < 4; ++n) {
      cacc[n] = __builtin_amdgcn_mfma_f32_16x16x32_bf16(a0, vf0[n], cacc[n], 0, 0, 0);
      cacc[n] = __builtin_amdgcn_mfma_f32_16x16x32_bf16(a1, vf1[n], cacc[n], 0, 0, 0);
    }
  }

#pragma unroll
  for (int n = 0; n < 4; ++n) {
#pragma unroll
    for (int r = 0; r < 4; ++r) {
      const int ss = q0 + w * 16 + lg * 4 + r;
      const int col = h * 64 + n * 16 + lr;
      ctx[((size_t)b * 2048 + ss) * 1024 + col] = f2bf(cacc[n][r]);
    }
  }
#undef STAGE
}

extern "C" void kernel_launch(void* const* d_in, const int* in_sizes, int n_in,
                              void* d_out, int out_size, void* d_ws, size_t ws_size,
                              hipStream_t stream) {
  const float* query = (const float*)d_in[0];
  const float* key   = (const float*)d_in[1];
  const float* value = (const float*)d_in[2];
  const float* mask  = (const float*)d_in[3];
  const float* wq = (const float*)d_in[4];
  const float* bq = (const float*)d_in[5];
  const float* wk = (const float*)d_in[6];
  const float* bk = (const float*)d_in[7];
  const float* wv = (const float*)d_in[8];
  const float* bv = (const float*)d_in[9];
  const float* wo = (const float*)d_in[10];
  const float* bo = (const float*)d_in[11];

  unsigned short* Qbf = (unsigned short*)d_ws;      // [B,H,S,64] bf16   8 MB
  unsigned short* Kbf = Qbf + 4194304;              // [B,H,S,64] bf16   8 MB
  unsigned short* Vtb = Kbf + 4194304;              // tiled V^T          8 MB
  unsigned short* ctx = Vtb + 4194304;              // [B,S,1024] bf16   8 MB
  unsigned short* wbf4 = ctx + 4194304;             // wq|wk|wv|wo bf16  8 MB
  int* flags = (int*)(wbf4 + 4194304);              // [B,32,32] flags   8 KB

  float* outp = (float*)d_out;            // [B,S,1024] fp32
  float* wout = outp + 4194304;           // [B,H,S,S] fp32

  prep<<<6144, 256, 0, stream>>>(mask, flags, wq, wk, wv, wo, wbf4);

  dim3 gq(8, 32, 3);
  gemm_qkv<<<gq, 256, 0, stream>>>(query, key, value, wbf4, bq, bk, bv, Qbf, Kbf, Vtb);

  attn_fused<<<512, 512, 0, stream>>>(Qbf, Kbf, Vtb, mask, flags, wout, ctx);

  dim3 gg(16, 32);
  gemm_out<<<gg, 256, 0, stream>>>(ctx, wbf4 + 3145728, bo, outp);
}

// Round 20
// 255.458 us; speedup vs baseline: 1.2235x; 1.0045x over previous
//
#include <hip/hip_runtime.h>
#include <cstdint>

typedef short bf16x8 __attribute__((ext_vector_type(8)));
typedef short bf16x4 __attribute__((ext_vector_type(4)));
typedef float f32x4 __attribute__((ext_vector_type(4)));

#define NEG_MAX 3.402823466e38f
#define C_EXP2 0.1803368801111244f  // 0.125 * log2(e)

__device__ __forceinline__ unsigned short f2bf(float f) {
  uint32_t u = __builtin_bit_cast(uint32_t, f);
  u += 0x7FFFu + ((u >> 16) & 1u);
  return (unsigned short)(u >> 16);
}

__device__ __forceinline__ float bf2f(unsigned short s) {
  return __builtin_bit_cast(float, (uint32_t)s << 16);
}

__device__ __forceinline__ bf16x8 pack8(float4 x, float4 y) {
  bf16x8 r;
  r[0] = (short)f2bf(x.x); r[1] = (short)f2bf(x.y); r[2] = (short)f2bf(x.z); r[3] = (short)f2bf(x.w);
  r[4] = (short)f2bf(y.x); r[5] = (short)f2bf(y.y); r[6] = (short)f2bf(y.z); r[7] = (short)f2bf(y.w);
  return r;
}

// Merged prep: blocks 0..2047 = mask_scan tiles; blocks 2048..6143 = weight cvt.
__global__ __launch_bounds__(256) void prep(const float* __restrict__ mask,
                                            int* __restrict__ flags,
                                            const float* __restrict__ wq, const float* __restrict__ wk,
                                            const float* __restrict__ wv, const float* __restrict__ wo,
                                            unsigned short* __restrict__ out) {
  const int blk = blockIdx.x;
  const int t = threadIdx.x;
  if (blk < 2048) {
    const int kt = blk & 31, qt = (blk >> 5) & 31, b = blk >> 10;
    const float* base = mask + ((size_t)b * 2048 + qt * 64) * 2048 + kt * 64;
    const int row = t >> 2, c0 = (t & 3) * 16;
    const float4* p = reinterpret_cast<const float4*>(base + (size_t)row * 2048 + c0);
    bool ones = true;
#pragma unroll
    for (int i = 0; i < 4; ++i) {
      float4 v = p[i];
      ones = ones && (v.x == 1.f) && (v.y == 1.f) && (v.z == 1.f) && (v.w == 1.f);
    }
    unsigned long long ball = __ballot(ones);
    __shared__ int sf[4];
    if ((t & 63) == 0) sf[t >> 6] = (ball == ~0ull) ? 1 : 0;
    __syncthreads();
    if (t == 0) flags[blk] = sf[0] & sf[1] & sf[2] & sf[3];
  } else {
    int i = (blk - 2048) * 256 + t;
    const int sel = i >> 18;
    const int idx = i & 0x3FFFF;
    const float* src = (sel == 0) ? wq : (sel == 1) ? wk : (sel == 2) ? wv : wo;
    float4 v = reinterpret_cast<const float4*>(src)[idx];
    ushort4 o;
    o.x = f2bf(v.x); o.y = f2bf(v.y); o.z = f2bf(v.z); o.w = f2bf(v.w);
    reinterpret_cast<ushort4*>(out)[i] = o;
  }
}

// Fused Q/K/V projection. z<2: head-split [B,H,S,64]; z==2: TILED V^T [B,H,32kt,64dk,64s].
__global__ __launch_bounds__(256) void gemm_qkv(const float* __restrict__ Aq,
                                                const float* __restrict__ Ak,
                                                const float* __restrict__ Av,
                                                const unsigned short* __restrict__ W3,
                                                const float* __restrict__ bq,
                                                const float* __restrict__ bk,
                                                const float* __restrict__ bv,
                                                unsigned short* __restrict__ Qbf,
                                                unsigned short* __restrict__ Kbf,
                                                unsigned short* __restrict__ Vtb) {
  constexpr int KD = 1024;
  __shared__ __align__(16) unsigned short Al[128 * 32];
  __shared__ __align__(16) unsigned short Bl[128 * 32];
  const int tid = threadIdx.x;
  const int l = tid & 63;
  const int w = tid >> 6;
  const int lr = l & 15;
  const int lg = l >> 4;
  const int gm = blockIdx.y;
  const int gn = blockIdx.x;
  const int z = blockIdx.z;
  const int wr = w >> 1;
  const int wc = w & 1;

  const float* Af = (z == 0) ? Aq : (z == 1) ? Ak : Av;
  const float* bias = (z == 0) ? bq : (z == 1) ? bk : bv;
  const unsigned short* Bw = W3 + (size_t)z * 1048576;
  unsigned short* Cb = (z == 0) ? Qbf : (z == 1) ? Kbf : Vtb;

  f32x4 acc[4][4];
#pragma unroll
  for (int m = 0; m < 4; ++m)
#pragma unroll
    for (int n = 0; n < 4; ++n) acc[m][n] = (f32x4){0.f, 0.f, 0.f, 0.f};

  const int c0 = w * 2;
  const int srow = (l >> 2);
  const int scol = (l & 3) * 8;
  const unsigned short* gB = Bw + (size_t)(gn * 128) * KD;

  const int arow = tid >> 1;
  const int ahalf = tid & 1;
  const float* gA = Af + (size_t)(gm * 128 + arow) * KD + ahalf * 16;

  float4 ap[4];
  {
    const float4* p = reinterpret_cast<const float4*>(gA);
#pragma unroll
    for (int i = 0; i < 4; ++i) ap[i] = p[i];
  }

  for (int kt = 0; kt < 32; ++kt) {
    const int k0 = kt * 32;
    const unsigned short* b0 = gB + (size_t)(c0 * 16 + srow) * KD + k0 + scol;
    const unsigned short* b1 = b0 + (size_t)16 * KD;
    __builtin_amdgcn_global_load_lds((const __attribute__((address_space(1))) void*)b0,
                                     (__attribute__((address_space(3))) void*)&Bl[c0 * 512], 16, 0, 0);
    __builtin_amdgcn_global_load_lds((const __attribute__((address_space(1))) void*)b1,
                                     (__attribute__((address_space(3))) void*)&Bl[c0 * 512 + 512], 16, 0, 0);
    {
      bf16x8* dst = reinterpret_cast<bf16x8*>(&Al[arow * 32 + ahalf * 16]);
      dst[0] = pack8(ap[0], ap[1]);
      dst[1] = pack8(ap[2], ap[3]);
    }
    __syncthreads();
    if (kt + 1 < 32) {
      const float4* p = reinterpret_cast<const float4*>(gA + (kt + 1) * 32);
#pragma unroll
      for (int i = 0; i < 4; ++i) ap[i] = p[i];
    }
    bf16x8 af[4], bfr[4];
#pragma unroll
    for (int m = 0; m < 4; ++m)
      af[m] = *reinterpret_cast<const bf16x8*>(&Al[(wr * 64 + m * 16 + lr) * 32 + lg * 8]);
#pragma unroll
    for (int n = 0; n < 4; ++n)
      bfr[n] = *reinterpret_cast<const bf16x8*>(&Bl[(wc * 64 + n * 16 + lr) * 32 + lg * 8]);
#pragma unroll
    for (int m = 0; m < 4; ++m)
#pragma unroll
      for (int n = 0; n < 4; ++n)
        acc[m][n] = __builtin_amdgcn_mfma_f32_16x16x32_bf16(af[m], bfr[n], acc[m][n], 0, 0, 0);
    __syncthreads();
  }

#pragma unroll
  for (int m = 0; m < 4; ++m) {
#pragma unroll
    for (int n = 0; n < 4; ++n) {
      const int colg = gn * 128 + wc * 64 + n * 16 + lr;
      const float bv2 = bias[colg];
#pragma unroll
      for (int r = 0; r < 4; ++r) {
        const int rowg = gm * 128 + wr * 64 + m * 16 + lg * 4 + r;
        const float v = acc[m][n][r] + bv2;
        const int bb = rowg >> 11, ss = rowg & 2047;
        const int hh = colg >> 6, dk = colg & 63;
        if (z < 2)
          Cb[(((size_t)bb * 16 + hh) * 2048 + ss) * 64 + dk] = f2bf(v);
        else
          Cb[(((size_t)bb * 16 + hh) * 32 + (ss >> 6)) * 4096 + (size_t)dk * 64 + (ss & 63)] = f2bf(v);
      }
    }
  }
}

// Output projection, 128x64 tiles, grid (16,32) = 512 blocks (2/CU), 4 waves (2x2).
__global__ __launch_bounds__(256) void gemm_out(const unsigned short* __restrict__ A,
                                                const unsigned short* __restrict__ Bw,
                                                const float* __restrict__ bias,
                                                float* __restrict__ Cf) {
  constexpr int KD = 1024;
  __shared__ __align__(16) unsigned short Al[128 * 32];
  __shared__ __align__(16) unsigned short Bl[64 * 32];
  const int tid = threadIdx.x;
  const int l = tid & 63;
  const int w = tid >> 6;          // 0..3
  const int lr = l & 15;
  const int lg = l >> 4;
  const int gm = blockIdx.y;
  const int gn = blockIdx.x;
  const int wr = w >> 1;
  const int wc = w & 1;

  f32x4 acc[4][2];
#pragma unroll
  for (int m = 0; m < 4; ++m)
#pragma unroll
    for (int n = 0; n < 2; ++n) acc[m][n] = (f32x4){0.f, 0.f, 0.f, 0.f};

  const int srow = (l >> 2);
  const int scol = (l & 3) * 8;
  const unsigned short* gA = A + (size_t)(gm * 128) * KD;
  const unsigned short* gB = Bw + (size_t)(gn * 64) * KD;

  for (int kt = 0; kt < 32; ++kt) {
    const int k0 = kt * 32;
    const unsigned short* a0 = gA + (size_t)(w * 32 + srow) * KD + k0 + scol;
    const unsigned short* a1 = a0 + (size_t)16 * KD;
    const unsigned short* b0 = gB + (size_t)(w * 16 + srow) * KD + k0 + scol;
    __builtin_amdgcn_global_load_lds((const __attribute__((address_space(1))) void*)a0,
                                     (__attribute__((address_space(3))) void*)&Al[w * 1024], 16, 0, 0);
    __builtin_amdgcn_global_load_lds((const __attribute__((address_space(1))) void*)a1,
                                     (__attribute__((address_space(3))) void*)&Al[w * 1024 + 512], 16, 0, 0);
    __builtin_amdgcn_global_load_lds((const __attribute__((address_space(1))) void*)b0,
                                     (__attribute__((address_space(3))) void*)&Bl[w * 512], 16, 0, 0);
    __syncthreads();
    bf16x8 af[4], bfr[2];
#pragma unroll
    for (int m = 0; m < 4; ++m)
      af[m] = *reinterpret_cast<const bf16x8*>(&Al[(wr * 64 + m * 16 + lr) * 32 + lg * 8]);
#pragma unroll
    for (int n = 0; n < 2; ++n)
      bfr[n] = *reinterpret_cast<const bf16x8*>(&Bl[(wc * 32 + n * 16 + lr) * 32 + lg * 8]);
#pragma unroll
    for (int m = 0; m < 4; ++m)
#pragma unroll
      for (int n = 0; n < 2; ++n)
        acc[m][n] = __builtin_amdgcn_mfma_f32_16x16x32_bf16(af[m], bfr[n], acc[m][n], 0, 0, 0);
    __syncthreads();
  }

#pragma unroll
  for (int m = 0; m < 4; ++m) {
#pragma unroll
    for (int n = 0; n < 2; ++n) {
      const int colg = gn * 64 + wc * 32 + n * 16 + lr;
      const float bv = bias[colg];
#pragma unroll
      for (int r = 0; r < 4; ++r) {
        const int rowg = gm * 128 + wr * 64 + m * 16 + lg * 4 + r;
        Cf[(size_t)rowg * 1024 + colg] = acc[m][n][r] + bv;
      }
    }
  }
}

// Attention: 512 blocks x 8 waves; ring-6 phase 1 (2 tiles/barrier);
// phase 2 NOW ring-3 K (slots 0-2) + ring-3 V (slots 3-5), staged 2 tiles ahead,
// exact FIFO-counted vmcnt; coalesced f32x4 NT weight stores.
__global__ __launch_bounds__(512, 4) void attn_fused(const unsigned short* __restrict__ Q,
                                                     const unsigned short* __restrict__ Kb,
                                                     const unsigned short* __restrict__ Vt,
                                                     const float* __restrict__ mask,
                                                     const int* __restrict__ flags,
                                                     float* __restrict__ wout,
                                                     unsigned short* __restrict__ ctx) {
  const int tid = threadIdx.x;
  const int l = tid & 63;
  const int w = tid >> 6;          // 0..7
  const int lr = l & 15;
  const int lg = l >> 4;

  const int d = blockIdx.x;
  const int bh = (d >> 7) * 8 + (d & 7);
  const int qp = (d >> 3) & 15;
  const int b = bh >> 4, h = bh & 15;
  const int q0 = qp * 128;

  __shared__ __align__(16) unsigned short KV[6][4096];   // 48 KB
  __shared__ __align__(16) unsigned short Wl[8][16][64]; // 16 KB, per-wave-private

  const size_t qoff = ((size_t)bh * 2048 + (q0 + w * 16 + lr)) * 64 + lg * 8;
  const bf16x8 qf0 = *reinterpret_cast<const bf16x8*>(Q + qoff);
  const bf16x8 qf1 = *reinterpret_cast<const bf16x8*>(Q + qoff + 32);

  const int seg = tid;
  const int rs = seg >> 3, cx = (seg & 7) ^ (rs & 7);
  const unsigned short* kB = Kb + (size_t)bh * 131072;
  const unsigned short* vB = Vt + (size_t)bh * 131072;
  const size_t tS = (size_t)rs * 64 + cx * 8;
  const int ldsOff = w * 512;

  const int sA = (lg ^ (lr & 7)) << 3;
  const int sBo = ((4 + lg) ^ (lr & 7)) << 3;

  const int fbase = (b * 32 + qp * 2 + (w >> 2)) * 32;
  const uint32_t fmask = (uint32_t)__ballot(flags[fbase + (l & 31)] != 0);

  const float* mbase = mask + (size_t)b * 2048 * 2048;

  const int lc = l & 15;
  const int wsub = (lc & 1) * 4;
  const int wcch = lc >> 1;

#define STAGE(base_, kt_, slot_)                                                                       \
  do {                                                                                                 \
    __builtin_amdgcn_global_load_lds(                                                                  \
        (const __attribute__((address_space(1))) void*)((base_) + (size_t)(kt_) * 4096 + tS),          \
        (__attribute__((address_space(3))) void*)(&KV[slot_][0] + ldsOff), 16, 0, 0);                  \
  } while (0)

  float s0[4] = {0.f, 0.f, 0.f, 0.f};

  // ---------------- Phase 1: denominators (ring-6, 2 tiles/barrier) ----------------
  STAGE(kB, 0, 0);
  STAGE(kB, 1, 1);
  STAGE(kB, 2, 2);
  STAGE(kB, 3, 3);
  for (int it = 0; it < 16; ++it) {
    if (it < 15) {
      asm volatile("s_waitcnt vmcnt(2)" ::: "memory");
    } else {
      asm volatile("s_waitcnt vmcnt(0)" ::: "memory");
    }
    __builtin_amdgcn_s_barrier();
    __builtin_amdgcn_sched_barrier(0);
    const int kt0 = it * 2;
#pragma unroll
    for (int half = 0; half < 2; ++half) {
      const int kt = kt0 + half;
      const unsigned short* Ks = &KV[kt % 6][0];
      bf16x8 kf0[4], kf1[4];
#pragma unroll
      for (int n = 0; n < 4; ++n) {
        const int rb = (n * 16 + lr) * 64;
        kf0[n] = *reinterpret_cast<const bf16x8*>(&Ks[rb + sA]);
        kf1[n] = *reinterpret_cast<const bf16x8*>(&Ks[rb + sBo]);
      }
      if (kt + 4 < 32) STAGE(kB, kt + 4, (kt + 4) % 6);
      f32x4 acc[4];
#pragma unroll
      for (int n = 0; n < 4; ++n) {
        acc[n] = (f32x4){0.f, 0.f, 0.f, 0.f};
        acc[n] = __builtin_amdgcn_mfma_f32_16x16x32_bf16(qf0, kf0[n], acc[n], 0, 0, 0);
        acc[n] = __builtin_amdgcn_mfma_f32_16x16x32_bf16(qf1, kf1[n], acc[n], 0, 0, 0);
      }
      if ((fmask >> kt) & 1) {
#pragma unroll
        for (int r = 0; r < 4; ++r)
          s0[r] += exp2f(acc[0][r] * C_EXP2) + exp2f(acc[1][r] * C_EXP2) +
                   exp2f(acc[2][r] * C_EXP2) + exp2f(acc[3][r] * C_EXP2);
      } else {
#pragma unroll
        for (int r = 0; r < 4; ++r) {
          const int qrow = q0 + w * 16 + lg * 4 + r;
          const float* mp = mbase + (size_t)qrow * 2048 + kt * 64;
          float ps = 0.f;
#pragma unroll
          for (int n = 0; n < 4; ++n) {
            const float mv = mp[n * 16 + lr];
            ps += __expf(acc[n][r] * 0.125f + (1.0f - mv) * (-NEG_MAX));
          }
          s0[r] += ps;
        }
      }
    }
  }

  float inv_s[4];
#pragma unroll
  for (int r = 0; r < 4; ++r) {
#pragma unroll
    for (int dd = 1; dd < 16; dd <<= 1) s0[r] += __shfl_xor(s0[r], dd);
    inv_s[r] = 1.0f / s0[r];
  }

  f32x4 cacc[4];
#pragma unroll
  for (int n = 0; n < 4; ++n) cacc[n] = (f32x4){0.f, 0.f, 0.f, 0.f};

  // ---------------- Phase 2: weights + PV (ring-3 K + ring-3 V, 2 tiles ahead) ----------------
  STAGE(kB, 0, 0);
  STAGE(vB, 0, 3);
  STAGE(kB, 1, 1);
  STAGE(vB, 1, 4);
  for (int kt = 0; kt < 32; ++kt) {
    if (kt == 0) {
      asm volatile("s_waitcnt vmcnt(2)" ::: "memory");
    } else if (kt == 1) {
      asm volatile("s_waitcnt vmcnt(6)" ::: "memory");
    } else if (kt <= 30) {
      asm volatile("s_waitcnt vmcnt(10)" ::: "memory");
    } else {
      asm volatile("s_waitcnt vmcnt(8)" ::: "memory");
    }
    __builtin_amdgcn_s_barrier();
    __builtin_amdgcn_sched_barrier(0);
    const unsigned short* Ks = &KV[kt % 3][0];
    const unsigned short* Vs = &KV[3 + kt % 3][0];
    bf16x8 kf0[4], kf1[4];
#pragma unroll
    for (int n = 0; n < 4; ++n) {
      const int rb = (n * 16 + lr) * 64;
      kf0[n] = *reinterpret_cast<const bf16x8*>(&Ks[rb + sA]);
      kf1[n] = *reinterpret_cast<const bf16x8*>(&Ks[rb + sBo]);
    }
    if (kt + 2 < 32) {
      STAGE(kB, kt + 2, (kt + 2) % 3);
      STAGE(vB, kt + 2, 3 + (kt + 2) % 3);
    }
    f32x4 acc[4];
#pragma unroll
    for (int n = 0; n < 4; ++n) {
      acc[n] = (f32x4){0.f, 0.f, 0.f, 0.f};
      acc[n] = __builtin_amdgcn_mfma_f32_16x16x32_bf16(qf0, kf0[n], acc[n], 0, 0, 0);
      acc[n] = __builtin_amdgcn_mfma_f32_16x16x32_bf16(qf1, kf1[n], acc[n], 0, 0, 0);
    }
    const int fl = (fmask >> kt) & 1;
#pragma unroll
    for (int r = 0; r < 4; ++r) {
      const int row2 = lg * 4 + r;
      const int rx = (row2 & 7) << 3;
      if (fl) {
#pragma unroll
        for (int n = 0; n < 4; ++n) {
          const float wgt = exp2f(acc[n][r] * C_EXP2) * inv_s[r];
          Wl[w][row2][(n * 16 + lr) ^ rx] = f2bf(wgt);
        }
      } else {
        const int qrow = q0 + w * 16 + row2;
        const float* mp = mbase + (size_t)qrow * 2048 + kt * 64;
#pragma unroll
        for (int n = 0; n < 4; ++n) {
          const float mv = mp[n * 16 + lr];
          const float wgt = __expf(acc[n][r] * 0.125f + (1.0f - mv) * (-NEG_MAX)) * inv_s[r];
          Wl[w][row2][(n * 16 + lr) ^ rx] = f2bf(wgt);
        }
      }
    }
    bf16x8 vf0[4], vf1[4];
#pragma unroll
    for (int n = 0; n < 4; ++n) {
      const int rb = (n * 16 + lr) * 64;
      vf0[n] = *reinterpret_cast<const bf16x8*>(&Vs[rb + sA]);
      vf1[n] = *reinterpret_cast<const bf16x8*>(&Vs[rb + sBo]);
    }
    asm volatile("s_waitcnt lgkmcnt(0)" ::: "memory");
    __builtin_amdgcn_sched_barrier(0);
    // W readback -> coalesced f32x4 NT stores
    {
#pragma unroll
      for (int i = 0; i < 4; ++i) {
        const int row = i * 4 + (l >> 4);
        const int addr = ((wcch ^ (row & 7)) << 3) + wsub;
        const bf16x4 wb = *reinterpret_cast<const bf16x4*>(&Wl[w][row][addr]);
        f32x4 fo;
        fo[0] = bf2f((unsigned short)wb[0]);
        fo[1] = bf2f((unsigned short)wb[1]);
        fo[2] = bf2f((unsigned short)wb[2]);
        fo[3] = bf2f((unsigned short)wb[3]);
        f32x4* wpv = reinterpret_cast<f32x4*>(
            wout + ((size_t)bh * 2048 + q0 + w * 16 + row) * 2048 + kt * 64 + lc * 4);
        __builtin_nontemporal_store(fo, wpv);
      }
    }
    const bf16x8 a0 = *reinterpret_cast<const bf16x8*>(&Wl[w][lr][(lg ^ (lr & 7)) * 8]);
    const bf16x8 a1 = *reinterpret_cast<const bf16x8*>(&Wl[w][lr][((4 | lg) ^ (lr & 7)) * 8]);
#pragma unroll
    for (int n = 0; n < 4; ++n) {
      cacc[n] = __builtin_amdgcn_mfma_f32_16x16x32_bf16(a0, vf0[n], cacc[n], 0, 0, 0);
      cacc[n] = __builtin_amdgcn_mfma_f32_16x16x32_bf16(a1, vf1[n], cacc[n], 0, 0, 0);
    }
  }

#pragma unroll
  for (int n = 0; n < 4; ++n) {
#pragma unroll
    for (int r = 0; r < 4; ++r) {
      const int ss = q0 + w * 16 + lg * 4 + r;
      const int col = h * 64 + n * 16 + lr;
      ctx[((size_t)b * 2048 + ss) * 1024 + col] = f2bf(cacc[n][r]);
    }
  }
#undef STAGE
}

extern "C" void kernel_launch(void* const* d_in, const int* in_sizes, int n_in,
                              void* d_out, int out_size, void* d_ws, size_t ws_size,
                              hipStream_t stream) {
  const float* query = (const float*)d_in[0];
  const float* key   = (const float*)d_in[1];
  const float* value = (const float*)d_in[2];
  const float* mask  = (const float*)d_in[3];
  const float* wq = (const float*)d_in[4];
  const float* bq = (const float*)d_in[5];
  const float* wk = (const float*)d_in[6];
  const float* bk = (const float*)d_in[7];
  const float* wv = (const float*)d_in[8];
  const float* bv = (const float*)d_in[9];
  const float* wo = (const float*)d_in[10];
  const float* bo = (const float*)d_in[11];

  unsigned short* Qbf = (unsigned short*)d_ws;      // [B,H,S,64] bf16   8 MB
  unsigned short* Kbf = Qbf + 4194304;              // [B,H,S,64] bf16   8 MB
  unsigned short* Vtb = Kbf + 4194304;              // tiled V^T          8 MB
  unsigned short* ctx = Vtb + 4194304;              // [B,S,1024] bf16   8 MB
  unsigned short* wbf4 = ctx + 4194304;             // wq|wk|wv|wo bf16  8 MB
  int* flags = (int*)(wbf4 + 4194304);              // [B,32,32] flags   8 KB

  float* outp = (float*)d_out;            // [B,S,1024] fp32
  float* wout = outp + 4194304;           // [B,H,S,S] fp32

  prep<<<6144, 256, 0, stream>>>(mask, flags, wq, wk, wv, wo, wbf4);

  dim3 gq(8, 32, 3);
  gemm_qkv<<<gq, 256, 0, stream>>>(query, key, value, wbf4, bq, bk, bv, Qbf, Kbf, Vtb);

  attn_fused<<<512, 512, 0, stream>>>(Qbf, Kbf, Vtb, mask, flags, wout, ctx);

  dim3 gg(16, 32);
  gemm_out<<<gg, 256, 0, stream>>>(ctx, wbf4 + 3145728, bo, outp);
}